// Round 2
// baseline (7051.752 us; speedup 1.0000x reference)
//
#include <hip/hip_runtime.h>
#include <cstdint>
#include <cstddef>

#define HID   32
#define TLEN  4096
#define DIN   8
#define DOUT  80

typedef float v2f __attribute__((ext_vector_type(2)));
typedef unsigned uv2 __attribute__((ext_vector_type(2)));

// sigmoid(x) = 1/(1+2^(-x*log2e)); saturates correctly at +-inf
__device__ __forceinline__ float fsig(float x) {
    float e = __builtin_amdgcn_exp2f(-1.442695041f * x);
    return __builtin_amdgcn_rcpf(1.0f + e);
}
__device__ __forceinline__ float bfbits(unsigned v) {
    union { unsigned u; float f; } c; c.u = v << 16; return c.f;
}
// dtype-agnostic scalar element load
__device__ __forceinline__ float ldf(const void* p, int idx, int isbf) {
    if (isbf) return bfbits(((const unsigned short*)p)[idx]);
    return ((const float*)p)[idx];
}
// Runtime dtype sniff (unchanged from verified version).
__device__ __forceinline__ int tensor_is_bf16(const void* p, int elems, int lane) {
    int nw = elems >> 1; if (nw > 64) nw = 64;
    int e = 0;
    if (lane < nw) {
        unsigned w = ((const unsigned*)p)[lane];
        e = (int)((w >> 7) & 0xFF);
    }
    return __ballot(e >= 135) == 0ULL;
}

__device__ __forceinline__ int rdlane_i(int v, int l) {
#if __has_builtin(__builtin_amdgcn_readlane)
    return __builtin_amdgcn_readlane(v, l);
#else
    return __shfl(v, l);
#endif
}
// Wave-uniform broadcast of lane l's value (l compile-time const) — v_readlane_b32.
__device__ __forceinline__ float rdlane(float v, int l) {
    return __int_as_float(rdlane_i(__float_as_int(v), l));
}

// pull_upper: lanes 0..31 receive the value held by lane+32. Implemented with
// v_permlane32_swap_b32 (pure VALU, single instruction producing both the
// upper-broadcast and lower-broadcast of v when both operands are v). Which
// result element is the upper-broadcast is resolved ONCE at runtime by a
// self-probe (sel), making this robust to either operand-role convention.
// Fallback: __shfl_xor (ds_bpermute) — always correct.
__device__ __forceinline__ float pull_upper(float v, int sel) {
#if __has_builtin(__builtin_amdgcn_permlane32_swap)
    uv2 r = __builtin_amdgcn_permlane32_swap(__float_as_uint(v), __float_as_uint(v),
                                             false, false);
    return __uint_as_float(sel ? r.x : r.y);
#else
    (void)sel;
    return __shfl_xor(v, 32);
#endif
}
// One-time probe: with v=lane, the upper-broadcast element holds 32 at lane 0.
__device__ __forceinline__ int probe_swap_sel(int lane) {
#if __has_builtin(__builtin_amdgcn_permlane32_swap)
    uv2 r = __builtin_amdgcn_permlane32_swap((unsigned)lane, (unsigned)lane,
                                             false, false);
    return (rdlane_i((int)r.x, 0) == 32) ? 1 : 0;
#else
    return 0;
#endif
}

// One wave per batch element. Lane j owns gate rows j and j+64 of each 128-row
// gate matrix: lane j<32 holds (i_j, g_j), lane j+32 holds (f_j, o_j).
// Packed float2 weights -> v_pk_fma_f32 (2 rows per instruction).
// NO LDS, NO barriers: h broadcast by readlane from lanes 0..31, f/o pulled
// down by permlane32_swap. Nothing in the loop drains vmcnt.
__global__ __launch_bounds__(64, 1)
void lstm_seq_kernel(const void* __restrict__ gx,
                     const void* __restrict__ gWih1,
                     const void* __restrict__ gWhh1,
                     const void* __restrict__ gbih1,
                     const void* __restrict__ gbhh1,
                     const void* __restrict__ gWih2,
                     const void* __restrict__ gWhh2,
                     const void* __restrict__ gbih2,
                     const void* __restrict__ gbhh2,
                     const void* __restrict__ gWlin,
                     const void* __restrict__ gblin,
                     float* __restrict__ gout,
                     int xelems)
{
    const int lane = threadIdx.x;
    const int b    = blockIdx.x;

    // resolve permlane32_swap result-element convention (wave-uniform)
    const int psel = probe_swap_sel(lane);

    // ---- per-tensor dtype detection (wave-uniform, identical in all blocks) ----
    const int xbf  = tensor_is_bf16(gx,    xelems,    lane);
    const int w1bf = tensor_is_bf16(gWih1, 4*HID*DIN, lane);
    const int h1bf = tensor_is_bf16(gWhh1, 4*HID*HID, lane);
    const int a1bf = tensor_is_bf16(gbih1, 4*HID,     lane);
    const int c1bf = tensor_is_bf16(gbhh1, 4*HID,     lane);
    const int w2bf = tensor_is_bf16(gWih2, 4*HID*HID, lane);
    const int h2bf = tensor_is_bf16(gWhh2, 4*HID*HID, lane);
    const int a2bf = tensor_is_bf16(gbih2, 4*HID,     lane);
    const int c2bf = tensor_is_bf16(gbhh2, 4*HID,     lane);
    const int wlbf = tensor_is_bf16(gWlin, DOUT*HID,  lane);
    const int blbf = tensor_is_bf16(gblin, DOUT,      lane);

    const int r0 = lane;        // i (lane<32) / f (lane>=32)
    const int r1 = lane + 64;   // g (lane<32) / o (lane>=32)

    float ra[HID], rb[HID];
    auto load32 = [&](const void* W, int row, int isbf, float* dst) {
#pragma unroll
        for (int k = 0; k < HID; ++k) dst[k] = ldf(W, row * HID + k, isbf);
    };

    // ---- stage all weights into registers (fp32, float2-packed over rows) ----
    v2f wih1[DIN];
#pragma unroll
    for (int k = 0; k < DIN; ++k)
        wih1[k] = (v2f){ ldf(gWih1, r0 * DIN + k, w1bf),
                         ldf(gWih1, r1 * DIN + k, w1bf) };

    v2f whh1[HID], wih2[HID], whh2[HID], wlin[HID];
    load32(gWhh1, r0, h1bf, ra); load32(gWhh1, r1, h1bf, rb);
#pragma unroll
    for (int k = 0; k < HID; ++k) whh1[k] = (v2f){ ra[k], rb[k] };
    load32(gWih2, r0, w2bf, ra); load32(gWih2, r1, w2bf, rb);
#pragma unroll
    for (int k = 0; k < HID; ++k) wih2[k] = (v2f){ ra[k], rb[k] };
    load32(gWhh2, r0, h2bf, ra); load32(gWhh2, r1, h2bf, rb);
#pragma unroll
    for (int k = 0; k < HID; ++k) whh2[k] = (v2f){ ra[k], rb[k] };
    {
        int rlo = lane;                                  // rows 0..63
        int rhi = (lane < DOUT - 64) ? lane + 64 : lane; // rows 64..79 on lanes 0..15
        load32(gWlin, rlo, wlbf, ra); load32(gWlin, rhi, wlbf, rb);
#pragma unroll
        for (int k = 0; k < HID; ++k) wlin[k] = (v2f){ ra[k], rb[k] };
    }

    v2f bias1 = { ldf(gbih1, r0, a1bf) + ldf(gbhh1, r0, c1bf),
                  ldf(gbih1, r1, a1bf) + ldf(gbhh1, r1, c1bf) };
    v2f bias2 = { ldf(gbih2, r0, a2bf) + ldf(gbhh2, r0, c2bf),
                  ldf(gbih2, r1, a2bf) + ldf(gbhh2, r1, c2bf) };
    v2f biasl = { ldf(gblin, lane, blbf),
                  (lane < 16) ? ldf(gblin, lane + 64, blbf) : 0.0f };

    // Per-lane activation constants for the packed .y gate component:
    // low lanes (g gate) need tanh, high lanes (o gate) need sigmoid.
    // tanh(x) = 2*sig(2x)-1, so: e=exp2(eY*x); r=rcp(1+e); B = r*mY + aY.
    const float eY = (lane < HID) ? -2.885390082f : -1.442695041f;
    const float mY = (lane < HID) ?  2.0f : 1.0f;
    const float aY = (lane < HID) ? -1.0f : 0.0f;

    // x: 8 values per step, wave-uniform address; width depends on dtype
    const char* xbase = (const char*)gx +
        (size_t)b * TLEN * DIN * (xbf ? 2 : 4);
    auto load_x = [&](float* d, int t) {
        if (xbf) {
            uint4 u = ((const uint4*)xbase)[t];          // 8 bf16 = 16B
            d[0] = bfbits(u.x & 0xffffu); d[1] = bfbits(u.x >> 16);
            d[2] = bfbits(u.y & 0xffffu); d[3] = bfbits(u.y >> 16);
            d[4] = bfbits(u.z & 0xffffu); d[5] = bfbits(u.z >> 16);
            d[6] = bfbits(u.w & 0xffffu); d[7] = bfbits(u.w >> 16);
        } else {
            float4 a = ((const float4*)xbase)[2*t];      // 8 fp32 = 32B
            float4 c = ((const float4*)xbase)[2*t + 1];
            d[0] = a.x; d[1] = a.y; d[2] = a.z; d[3] = a.w;
            d[4] = c.x; d[5] = c.y; d[6] = c.z; d[7] = c.w;
        }
    };
    // bias1 + Wih1 . x — independent of the recurrence, 2 partial chains
    auto xgate = [&](const float* xv) -> v2f {
        v2f u0 = {0.0f, 0.0f}, u1 = {0.0f, 0.0f};
#pragma unroll
        for (int k = 0; k < DIN; k += 2) {
            v2f s0 = { xv[k],   xv[k]   };
            v2f s1 = { xv[k+1], xv[k+1] };
            u0 += wih1[k]   * s0;
            u1 += wih1[k+1] * s1;
        }
        return bias1 + (u0 + u1);
    };

    float* outp = gout + (size_t)b * TLEN * DOUT;

    float c1 = 0.0f, c2 = 0.0f;          // valid on lanes<32; junk elsewhere (never read)
    v2f p1a = {0,0}, p1b = {0,0};        // Whh1 . h1_{t-1} partials
    v2f p2a = {0,0}, p2b = {0,0};        // Whh2 . h2_{t-1} partials

    // x pipeline: g1base ready for step t; xn1 = x(t+1); xn2 = x(t+2);
    // load of x(t+3) issued each step -> ~2 full iterations in flight (>HBM lat).
    float xn1[DIN], xn2[DIN];
    v2f g1base;
    {
        float x0[DIN];
        load_x(x0, 0);
        load_x(xn1, 1);
        load_x(xn2, 2);
        g1base = xgate(x0);
    }

#pragma unroll 1
    for (int t = 0; t < TLEN; ++t) {
        // issue far prefetch early; consumed 2 iterations from now
        float xn3[DIN] = {0,0,0,0,0,0,0,0};
        if (t + 3 < TLEN) load_x(xn3, t + 3);

        // ---- layer-1 gates: pre1 (from last iter's round 1) + bias + Wih1.x ----
        v2f g1 = (p1a + p1b) + g1base;

        // activations BEFORE the cross-lane swap:
        // all lanes: A = sig(.x)  (low: sig(i), high: sig(f))
        //            B = tanh/sig(.y) via per-lane consts (low: tanh(g), high: sig(o))
        float A1 = fsig(g1.x);
        float e1 = __builtin_amdgcn_exp2f(eY * g1.y);
        float B1 = fmaf(__builtin_amdgcn_rcpf(1.0f + e1), mY, aY);
        float sf1 = pull_upper(A1, psel);    // sig(f) -> low lanes
        float so1 = pull_upper(B1, psel);    // sig(o) -> low lanes
        c1 = fmaf(sf1, c1, A1 * B1);         // sig(f)*c + sig(i)*tanh(g)
        float ec1 = __builtin_amdgcn_exp2f(-2.885390082f * c1);
        float h1n = so1 * fmaf(__builtin_amdgcn_rcpf(1.0f + ec1), 2.0f, -1.0f);

        // independent filler work: next step's x-gates (uses x(t+1))
        v2f g1b_next = xgate(xn1);

        // ---- h1 broadcast (readlane) + round 1: g2 (Wih2) AND next pre1 (Whh1) ----
        v2f q0 = {0,0}, q1 = {0,0};      // g2 partials
        v2f n0 = {0,0}, n1 = {0,0};      // pre1 partials
#pragma unroll
        for (int k = 0; k < HID; k += 2) {
            float h0 = rdlane(h1n, k);
            float h1v = rdlane(h1n, k + 1);
            v2f s0 = { h0, h0 }, s1 = { h1v, h1v };
            q0 += wih2[k]   * s0;  n0 += whh1[k]   * s0;
            q1 += wih2[k+1] * s1;  n1 += whh1[k+1] * s1;
        }
        p1a = n0; p1b = n1;
        v2f g2 = (q0 + q1) + ((p2a + p2b) + bias2);

        // ---- layer-2 cell update ----
        float A2 = fsig(g2.x);
        float e2 = __builtin_amdgcn_exp2f(eY * g2.y);
        float B2 = fmaf(__builtin_amdgcn_rcpf(1.0f + e2), mY, aY);
        float sf2 = pull_upper(A2, psel);
        float so2 = pull_upper(B2, psel);
        c2 = fmaf(sf2, c2, A2 * B2);
        float ec2 = __builtin_amdgcn_exp2f(-2.885390082f * c2);
        float h2n = so2 * fmaf(__builtin_amdgcn_rcpf(1.0f + ec2), 2.0f, -1.0f);

        // ---- h2 broadcast + round 2: output proj (Wlin) AND next pre2 (Whh2) ----
        v2f o0 = biasl, o1 = {0,0};
        v2f m0 = {0,0}, m1 = {0,0};
#pragma unroll
        for (int k = 0; k < HID; k += 2) {
            float h0 = rdlane(h2n, k);
            float h1v = rdlane(h2n, k + 1);
            v2f s0 = { h0, h0 }, s1 = { h1v, h1v };
            o0 += wlin[k]   * s0;  m0 += whh2[k]   * s0;
            o1 += wlin[k+1] * s1;  m1 += whh2[k+1] * s1;
        }
        p2a = m0; p2b = m1;
        v2f oacc = o0 + o1;

        float* op = outp + (size_t)t * DOUT;
        op[lane] = oacc.x;                       // rows 0..63
        if (lane < 16) op[64 + lane] = oacc.y;   // rows 64..79

        // rotate x pipeline
        g1base = g1b_next;
#pragma unroll
        for (int k = 0; k < DIN; ++k) { xn1[k] = xn2[k]; xn2[k] = xn3[k]; }
    }
}

extern "C" void kernel_launch(void* const* d_in, const int* in_sizes, int n_in,
                              void* d_out, int out_size, void* d_ws, size_t ws_size,
                              hipStream_t stream)
{
    float* out = (float*)d_out;
    const int xelems = in_sizes[0];
    const int B = xelems / (TLEN * DIN);   // 256 (element count, dtype-independent)
    lstm_seq_kernel<<<B, 64, 0, stream>>>(d_in[0], d_in[1], d_in[2], d_in[3],
                                          d_in[4], d_in[5], d_in[6], d_in[7],
                                          d_in[8], d_in[9], d_in[10],
                                          out, xelems);
}

// Round 3
// 6760.064 us; speedup vs baseline: 1.0431x; 1.0431x over previous
//
#include <hip/hip_runtime.h>
#include <cstdint>
#include <cstddef>

#define HID   32
#define TLEN  4096
#define DIN   8
#define DOUT  80

typedef float v2f __attribute__((ext_vector_type(2)));
typedef unsigned uv2 __attribute__((ext_vector_type(2)));

// sigmoid(x) = 1/(1+2^(-x*log2e)); saturates correctly at +-inf
__device__ __forceinline__ float fsig(float x) {
    float e = __builtin_amdgcn_exp2f(-1.442695041f * x);
    return __builtin_amdgcn_rcpf(1.0f + e);
}
__device__ __forceinline__ float bfbits(unsigned v) {
    union { unsigned u; float f; } c; c.u = v << 16; return c.f;
}
// dtype-agnostic scalar element load
__device__ __forceinline__ float ldf(const void* p, int idx, int isbf) {
    if (isbf) return bfbits(((const unsigned short*)p)[idx]);
    return ((const float*)p)[idx];
}
// Runtime dtype sniff (unchanged from verified version).
__device__ __forceinline__ int tensor_is_bf16(const void* p, int elems, int lane) {
    int nw = elems >> 1; if (nw > 64) nw = 64;
    int e = 0;
    if (lane < nw) {
        unsigned w = ((const unsigned*)p)[lane];
        e = (int)((w >> 7) & 0xFF);
    }
    return __ballot(e >= 135) == 0ULL;
}

__device__ __forceinline__ int rdlane_i(int v, int l) {
#if __has_builtin(__builtin_amdgcn_readlane)
    return __builtin_amdgcn_readlane(v, l);
#else
    return __shfl(v, l);
#endif
}
// Wave-uniform broadcast of lane l's value (l compile-time const) — v_readlane_b32.
__device__ __forceinline__ float rdlane(float v, int l) {
    return __int_as_float(rdlane_i(__float_as_int(v), l));
}

// pull_upper: lanes 0..31 receive the value held by lane+32 (verified correct
// in round 2 via runtime psel probe + passing harness).
__device__ __forceinline__ float pull_upper(float v, int sel) {
#if __has_builtin(__builtin_amdgcn_permlane32_swap)
    uv2 r = __builtin_amdgcn_permlane32_swap(__float_as_uint(v), __float_as_uint(v),
                                             false, false);
    return __uint_as_float(sel ? r.x : r.y);
#else
    (void)sel;
    return __shfl_xor(v, 32);
#endif
}
__device__ __forceinline__ int probe_swap_sel(int lane) {
#if __has_builtin(__builtin_amdgcn_permlane32_swap)
    uv2 r = __builtin_amdgcn_permlane32_swap((unsigned)lane, (unsigned)lane,
                                             false, false);
    return (rdlane_i((int)r.x, 0) == 32) ? 1 : 0;
#else
    return 0;
#endif
}

// Liveness pin: makes the staged value opaque so LLVM cannot rematerialize the
// global load inside the t-loop. Round-2 PMC showed VGPR_Count=152 << the ~350
// live weights -> compiler was RE-LOADING weights every timestep (VALUBusy 12%).
__device__ __forceinline__ void pin(v2f& v) { asm volatile("" : "+v"(v)); }
__device__ __forceinline__ void pinf(float& v) { asm volatile("" : "+v"(v)); }

// One wave per batch element. Lane j owns gate rows j and j+64 of each 128-row
// gate matrix: lane j<32 holds (i_j, g_j), lane j+32 holds (f_j, o_j).
// Packed float2 weights -> v_pk_fma_f32 (2 rows per instruction).
// NO LDS, NO barriers; all weights pinned resident in VGPRs.
__global__ __launch_bounds__(64, 1)
void lstm_seq_kernel(const void* __restrict__ gx,
                     const void* __restrict__ gWih1,
                     const void* __restrict__ gWhh1,
                     const void* __restrict__ gbih1,
                     const void* __restrict__ gbhh1,
                     const void* __restrict__ gWih2,
                     const void* __restrict__ gWhh2,
                     const void* __restrict__ gbih2,
                     const void* __restrict__ gbhh2,
                     const void* __restrict__ gWlin,
                     const void* __restrict__ gblin,
                     float* __restrict__ gout,
                     int xelems)
{
    const int lane = threadIdx.x;
    const int b    = blockIdx.x;

    const int psel = probe_swap_sel(lane);

    // ---- per-tensor dtype detection (wave-uniform, identical in all blocks) ----
    const int xbf  = tensor_is_bf16(gx,    xelems,    lane);
    const int w1bf = tensor_is_bf16(gWih1, 4*HID*DIN, lane);
    const int h1bf = tensor_is_bf16(gWhh1, 4*HID*HID, lane);
    const int a1bf = tensor_is_bf16(gbih1, 4*HID,     lane);
    const int c1bf = tensor_is_bf16(gbhh1, 4*HID,     lane);
    const int w2bf = tensor_is_bf16(gWih2, 4*HID*HID, lane);
    const int h2bf = tensor_is_bf16(gWhh2, 4*HID*HID, lane);
    const int a2bf = tensor_is_bf16(gbih2, 4*HID,     lane);
    const int c2bf = tensor_is_bf16(gbhh2, 4*HID,     lane);
    const int wlbf = tensor_is_bf16(gWlin, DOUT*HID,  lane);
    const int blbf = tensor_is_bf16(gblin, DOUT,      lane);

    const int r0 = lane;        // i (lane<32) / f (lane>=32)
    const int r1 = lane + 64;   // g (lane<32) / o (lane>=32)

    float ra[HID], rb[HID];
    auto load32 = [&](const void* W, int row, int isbf, float* dst) {
#pragma unroll
        for (int k = 0; k < HID; ++k) dst[k] = ldf(W, row * HID + k, isbf);
    };

    // ---- stage all weights into registers (fp32, float2-packed over rows) ----
    v2f wih1[DIN];
#pragma unroll
    for (int k = 0; k < DIN; ++k)
        wih1[k] = (v2f){ ldf(gWih1, r0 * DIN + k, w1bf),
                         ldf(gWih1, r1 * DIN + k, w1bf) };

    v2f whh1[HID], wih2[HID], whh2[HID], wlin[HID];
    load32(gWhh1, r0, h1bf, ra); load32(gWhh1, r1, h1bf, rb);
#pragma unroll
    for (int k = 0; k < HID; ++k) whh1[k] = (v2f){ ra[k], rb[k] };
    load32(gWih2, r0, w2bf, ra); load32(gWih2, r1, w2bf, rb);
#pragma unroll
    for (int k = 0; k < HID; ++k) wih2[k] = (v2f){ ra[k], rb[k] };
    load32(gWhh2, r0, h2bf, ra); load32(gWhh2, r1, h2bf, rb);
#pragma unroll
    for (int k = 0; k < HID; ++k) whh2[k] = (v2f){ ra[k], rb[k] };
    {
        int rlo = lane;                                  // rows 0..63
        int rhi = (lane < DOUT - 64) ? lane + 64 : lane; // rows 64..79 on lanes 0..15
        load32(gWlin, rlo, wlbf, ra); load32(gWlin, rhi, wlbf, rb);
#pragma unroll
        for (int k = 0; k < HID; ++k) wlin[k] = (v2f){ ra[k], rb[k] };
    }

    v2f bias1 = { ldf(gbih1, r0, a1bf) + ldf(gbhh1, r0, c1bf),
                  ldf(gbih1, r1, a1bf) + ldf(gbhh1, r1, c1bf) };
    v2f bias2 = { ldf(gbih2, r0, a2bf) + ldf(gbhh2, r0, c2bf),
                  ldf(gbih2, r1, a2bf) + ldf(gbhh2, r1, c2bf) };
    v2f biasl = { ldf(gblin, lane, blbf),
                  (lane < 16) ? ldf(gblin, lane + 64, blbf) : 0.0f };

    // ---- pin everything staged: forces register residency across the t-loop ----
#pragma unroll
    for (int k = 0; k < DIN; ++k) pin(wih1[k]);
#pragma unroll
    for (int k = 0; k < HID; ++k) { pin(whh1[k]); pin(wih2[k]); pin(whh2[k]); pin(wlin[k]); }
    pin(bias1); pin(bias2); pin(biasl);

    // Per-lane activation constants for the packed .y gate component:
    // low lanes (g gate) need tanh, high lanes (o gate) need sigmoid.
    const float eY = (lane < HID) ? -2.885390082f : -1.442695041f;
    const float mY = (lane < HID) ?  2.0f : 1.0f;
    const float aY = (lane < HID) ? -1.0f : 0.0f;

    // x: 8 values per step, wave-uniform address; width depends on dtype
    const char* xbase = (const char*)gx +
        (size_t)b * TLEN * DIN * (xbf ? 2 : 4);
    auto load_x = [&](float* d, int t) {
        if (xbf) {
            uint4 u = ((const uint4*)xbase)[t];          // 8 bf16 = 16B
            d[0] = bfbits(u.x & 0xffffu); d[1] = bfbits(u.x >> 16);
            d[2] = bfbits(u.y & 0xffffu); d[3] = bfbits(u.y >> 16);
            d[4] = bfbits(u.z & 0xffffu); d[5] = bfbits(u.z >> 16);
            d[6] = bfbits(u.w & 0xffffu); d[7] = bfbits(u.w >> 16);
        } else {
            float4 a = ((const float4*)xbase)[2*t];      // 8 fp32 = 32B
            float4 c = ((const float4*)xbase)[2*t + 1];
            d[0] = a.x; d[1] = a.y; d[2] = a.z; d[3] = a.w;
            d[4] = c.x; d[5] = c.y; d[6] = c.z; d[7] = c.w;
        }
    };
    // bias1 + Wih1 . x — independent of the recurrence, 2 partial chains
    auto xgate = [&](const float* xv) -> v2f {
        v2f u0 = {0.0f, 0.0f}, u1 = {0.0f, 0.0f};
#pragma unroll
        for (int k = 0; k < DIN; k += 2) {
            v2f s0 = { xv[k],   xv[k]   };
            v2f s1 = { xv[k+1], xv[k+1] };
            u0 += wih1[k]   * s0;
            u1 += wih1[k+1] * s1;
        }
        return bias1 + (u0 + u1);
    };

    float* outp = gout + (size_t)b * TLEN * DOUT;

    float c1 = 0.0f, c2 = 0.0f;          // valid on lanes<32; junk elsewhere (never read)
    v2f p1a = {0,0}, p1b = {0,0};        // Whh1 . h1_{t-1} partials
    v2f p2a = {0,0}, p2b = {0,0};        // Whh2 . h2_{t-1} partials

    float xn1[DIN], xn2[DIN];
    v2f g1base;
    {
        float x0[DIN];
        load_x(x0, 0);
        load_x(xn1, 1);
        load_x(xn2, 2);
        g1base = xgate(x0);
    }

#pragma unroll 1
    for (int t = 0; t < TLEN; ++t) {
        // issue far prefetch early; consumed 2 iterations from now
        float xn3[DIN] = {0,0,0,0,0,0,0,0};
        if (t + 3 < TLEN) load_x(xn3, t + 3);

        // ---- layer-1 gates: pre1 (from last iter's round 1) + bias + Wih1.x ----
        v2f g1 = (p1a + p1b) + g1base;

        float A1 = fsig(g1.x);
        float e1 = __builtin_amdgcn_exp2f(eY * g1.y);
        float B1 = fmaf(__builtin_amdgcn_rcpf(1.0f + e1), mY, aY);
        float sf1 = pull_upper(A1, psel);    // sig(f) -> low lanes
        float so1 = pull_upper(B1, psel);    // sig(o) -> low lanes
        c1 = fmaf(sf1, c1, A1 * B1);         // sig(f)*c + sig(i)*tanh(g)
        float ec1 = __builtin_amdgcn_exp2f(-2.885390082f * c1);
        float h1n = so1 * fmaf(__builtin_amdgcn_rcpf(1.0f + ec1), 2.0f, -1.0f);

        // independent filler work: next step's x-gates (uses x(t+1))
        v2f g1b_next = xgate(xn1);

        // ---- h1 broadcast (readlane) + round 1: g2 (Wih2) AND next pre1 (Whh1) ----
        // 4 partials per target -> 8-deep dependent fma chains
        v2f q0 = {0,0}, q1 = {0,0}, q2 = {0,0}, q3 = {0,0};
        v2f n0 = {0,0}, n1 = {0,0}, n2 = {0,0}, n3 = {0,0};
#pragma unroll
        for (int k = 0; k < HID; k += 4) {
            float h0 = rdlane(h1n, k);
            float h1v = rdlane(h1n, k + 1);
            float h2v = rdlane(h1n, k + 2);
            float h3v = rdlane(h1n, k + 3);
            v2f s0 = { h0, h0 }, s1 = { h1v, h1v };
            v2f s2 = { h2v, h2v }, s3 = { h3v, h3v };
            q0 += wih2[k]   * s0;  n0 += whh1[k]   * s0;
            q1 += wih2[k+1] * s1;  n1 += whh1[k+1] * s1;
            q2 += wih2[k+2] * s2;  n2 += whh1[k+2] * s2;
            q3 += wih2[k+3] * s3;  n3 += whh1[k+3] * s3;
        }
        p1a = n0 + n1; p1b = n2 + n3;
        v2f g2 = ((q0 + q1) + (q2 + q3)) + ((p2a + p2b) + bias2);

        // ---- layer-2 cell update ----
        float A2 = fsig(g2.x);
        float e2 = __builtin_amdgcn_exp2f(eY * g2.y);
        float B2 = fmaf(__builtin_amdgcn_rcpf(1.0f + e2), mY, aY);
        float sf2 = pull_upper(A2, psel);
        float so2 = pull_upper(B2, psel);
        c2 = fmaf(sf2, c2, A2 * B2);
        float ec2 = __builtin_amdgcn_exp2f(-2.885390082f * c2);
        float h2n = so2 * fmaf(__builtin_amdgcn_rcpf(1.0f + ec2), 2.0f, -1.0f);

        // ---- h2 broadcast + round 2: output proj (Wlin) AND next pre2 (Whh2) ----
        v2f o0 = biasl, o1 = {0,0}, o2 = {0,0}, o3 = {0,0};
        v2f m0 = {0,0}, m1 = {0,0}, m2 = {0,0}, m3 = {0,0};
#pragma unroll
        for (int k = 0; k < HID; k += 4) {
            float h0 = rdlane(h2n, k);
            float h1v = rdlane(h2n, k + 1);
            float h2v = rdlane(h2n, k + 2);
            float h3v = rdlane(h2n, k + 3);
            v2f s0 = { h0, h0 }, s1 = { h1v, h1v };
            v2f s2 = { h2v, h2v }, s3 = { h3v, h3v };
            o0 += wlin[k]   * s0;  m0 += whh2[k]   * s0;
            o1 += wlin[k+1] * s1;  m1 += whh2[k+1] * s1;
            o2 += wlin[k+2] * s2;  m2 += whh2[k+2] * s2;
            o3 += wlin[k+3] * s3;  m3 += whh2[k+3] * s3;
        }
        p2a = m0 + m1; p2b = m2 + m3;
        v2f oacc = (o0 + o1) + (o2 + o3);

        float* op = outp + (size_t)t * DOUT;
        op[lane] = oacc.x;                       // rows 0..63
        if (lane < 16) op[64 + lane] = oacc.y;   // rows 64..79

        // rotate x pipeline
        g1base = g1b_next;
#pragma unroll
        for (int k = 0; k < DIN; ++k) { xn1[k] = xn2[k]; xn2[k] = xn3[k]; }
    }
}

extern "C" void kernel_launch(void* const* d_in, const int* in_sizes, int n_in,
                              void* d_out, int out_size, void* d_ws, size_t ws_size,
                              hipStream_t stream)
{
    float* out = (float*)d_out;
    const int xelems = in_sizes[0];
    const int B = xelems / (TLEN * DIN);   // 256 (element count, dtype-independent)
    lstm_seq_kernel<<<B, 64, 0, stream>>>(d_in[0], d_in[1], d_in[2], d_in[3],
                                          d_in[4], d_in[5], d_in[6], d_in[7],
                                          d_in[8], d_in[9], d_in[10],
                                          out, xelems);
}

// Round 4
// 5568.259 us; speedup vs baseline: 1.2664x; 1.2140x over previous
//
#include <hip/hip_runtime.h>
#include <cstdint>
#include <cstddef>

#define HID   32
#define TLEN  4096
#define DIN   8
#define DOUT  80

typedef unsigned uv2 __attribute__((ext_vector_type(2)));

// sigmoid(x) = 1/(1+2^(-x*log2e)); saturates correctly at +-inf
__device__ __forceinline__ float fsig(float x) {
    float e = __builtin_amdgcn_exp2f(-1.442695041f * x);
    return __builtin_amdgcn_rcpf(1.0f + e);
}
__device__ __forceinline__ float bfbits(unsigned v) {
    union { unsigned u; float f; } c; c.u = v << 16; return c.f;
}
// dtype-agnostic scalar element load
__device__ __forceinline__ float ldf(const void* p, int idx, int isbf) {
    if (isbf) return bfbits(((const unsigned short*)p)[idx]);
    return ((const float*)p)[idx];
}
// Runtime dtype sniff (verified rounds 2-3).
__device__ __forceinline__ int tensor_is_bf16(const void* p, int elems, int lane) {
    int nw = elems >> 1; if (nw > 64) nw = 64;
    int e = 0;
    if (lane < nw) {
        unsigned w = ((const unsigned*)p)[lane];
        e = (int)((w >> 7) & 0xFF);
    }
    return __ballot(e >= 135) == 0ULL;
}

__device__ __forceinline__ int rdlane_i(int v, int l) {
#if __has_builtin(__builtin_amdgcn_readlane)
    return __builtin_amdgcn_readlane(v, l);
#else
    return __shfl(v, l);
#endif
}
// Wave-uniform broadcast of lane l's value (l compile-time const) — v_readlane_b32.
__device__ __forceinline__ float rdlane(float v, int l) {
    return __int_as_float(rdlane_i(__float_as_int(v), l));
}

// pull_upper: lanes 0..31 receive the value held by lane+32 (verified correct
// rounds 2-3 via runtime psel probe + passing harness).
__device__ __forceinline__ float pull_upper(float v, int sel) {
#if __has_builtin(__builtin_amdgcn_permlane32_swap)
    uv2 r = __builtin_amdgcn_permlane32_swap(__float_as_uint(v), __float_as_uint(v),
                                             false, false);
    return __uint_as_float(sel ? r.x : r.y);
#else
    (void)sel;
    return __shfl_xor(v, 32);
#endif
}
__device__ __forceinline__ int probe_swap_sel(int lane) {
#if __has_builtin(__builtin_amdgcn_permlane32_swap)
    uv2 r = __builtin_amdgcn_permlane32_swap((unsigned)lane, (unsigned)lane,
                                             false, false);
    return (rdlane_i((int)r.x, 0) == 32) ? 1 : 0;
#else
    return 0;
#endif
}

// Liveness pin for VGPR-resident values (prevents load rematerialization).
__device__ __forceinline__ void pinf(float& v) { asm volatile("" : "+v"(v)); }

// AGPR residency: rounds 2-3 proved the allocator spills per-lane weight
// staging to scratch (VGPR_Count 156 << ~350 live; L1-thrashing reloads every
// timestep). AGPRs are a 256-reg file the allocator otherwise never touches on
// a non-MFMA kernel — stage the recurrence matrices there explicitly.
#define AWRITE(dst, src) asm volatile("v_accvgpr_write_b32 %0, %1" : "=a"(dst) : "v"(src))
#define AREAD(dst, src)  asm volatile("v_accvgpr_read_b32 %0, %1"  : "=v"(dst) : "a"(src))

// One wave per batch element. Lane j owns gate rows j and j+64 of each 128-row
// gate matrix: lane j<32 holds (i_j, g_j), lane j+32 holds (f_j, o_j).
// Whh1/Wih2/Whh2 live in AGPRs (192), Wlin/Wih1/biases in VGPRs.
// NO LDS, NO barriers; h broadcast via v_readlane, f/o via permlane32_swap.
__global__ __launch_bounds__(64) __attribute__((amdgpu_waves_per_eu(1, 1)))
void lstm_seq_kernel(const void* __restrict__ gx,
                     const void* __restrict__ gWih1,
                     const void* __restrict__ gWhh1,
                     const void* __restrict__ gbih1,
                     const void* __restrict__ gbhh1,
                     const void* __restrict__ gWih2,
                     const void* __restrict__ gWhh2,
                     const void* __restrict__ gbih2,
                     const void* __restrict__ gbhh2,
                     const void* __restrict__ gWlin,
                     const void* __restrict__ gblin,
                     float* __restrict__ gout,
                     int xelems)
{
    const int lane = threadIdx.x;
    const int b    = blockIdx.x;

    const int psel = probe_swap_sel(lane);

    // ---- per-tensor dtype detection (wave-uniform, identical in all blocks) ----
    const int xbf  = tensor_is_bf16(gx,    xelems,    lane);
    const int w1bf = tensor_is_bf16(gWih1, 4*HID*DIN, lane);
    const int h1bf = tensor_is_bf16(gWhh1, 4*HID*HID, lane);
    const int a1bf = tensor_is_bf16(gbih1, 4*HID,     lane);
    const int c1bf = tensor_is_bf16(gbhh1, 4*HID,     lane);
    const int w2bf = tensor_is_bf16(gWih2, 4*HID*HID, lane);
    const int h2bf = tensor_is_bf16(gWhh2, 4*HID*HID, lane);
    const int a2bf = tensor_is_bf16(gbih2, 4*HID,     lane);
    const int c2bf = tensor_is_bf16(gbhh2, 4*HID,     lane);
    const int wlbf = tensor_is_bf16(gWlin, DOUT*HID,  lane);
    const int blbf = tensor_is_bf16(gblin, DOUT,      lane);

    const int r0 = lane;        // i (lane<32) / f (lane>=32)
    const int r1 = lane + 64;   // g (lane<32) / o (lane>=32)

    float ra[HID], rb[HID];
    auto load32 = [&](const void* W, int row, int isbf, float* dst) {
#pragma unroll
        for (int k = 0; k < HID; ++k) dst[k] = ldf(W, row * HID + k, isbf);
    };

    // ---- AGPR-resident matrices: Whh1, Wih2, Whh2 (x = row r0, y = row r1) ----
    float Ahh1x[HID], Ahh1y[HID];
    float Aih2x[HID], Aih2y[HID];
    float Ahh2x[HID], Ahh2y[HID];

    load32(gWhh1, r0, h1bf, ra); load32(gWhh1, r1, h1bf, rb);
#pragma unroll
    for (int k = 0; k < HID; ++k) { AWRITE(Ahh1x[k], ra[k]); AWRITE(Ahh1y[k], rb[k]); }
    load32(gWih2, r0, w2bf, ra); load32(gWih2, r1, w2bf, rb);
#pragma unroll
    for (int k = 0; k < HID; ++k) { AWRITE(Aih2x[k], ra[k]); AWRITE(Aih2y[k], rb[k]); }
    load32(gWhh2, r0, h2bf, ra); load32(gWhh2, r1, h2bf, rb);
#pragma unroll
    for (int k = 0; k < HID; ++k) { AWRITE(Ahh2x[k], ra[k]); AWRITE(Ahh2y[k], rb[k]); }

    // ---- VGPR-resident: Wlin (off-recurrence; harmless if spilled), Wih1, biases ----
    float wlx[HID], wly[HID];
    {
        int rlo = lane;                                  // rows 0..63
        int rhi = (lane < DOUT - 64) ? lane + 64 : lane; // rows 64..79 on lanes 0..15
        load32(gWlin, rlo, wlbf, wlx); load32(gWlin, rhi, wlbf, wly);
    }
    float w1x[DIN], w1y[DIN];
#pragma unroll
    for (int k = 0; k < DIN; ++k) {
        w1x[k] = ldf(gWih1, r0 * DIN + k, w1bf);
        w1y[k] = ldf(gWih1, r1 * DIN + k, w1bf);
    }
    float b1x = ldf(gbih1, r0, a1bf) + ldf(gbhh1, r0, c1bf);
    float b1y = ldf(gbih1, r1, a1bf) + ldf(gbhh1, r1, c1bf);
    float b2x = ldf(gbih2, r0, a2bf) + ldf(gbhh2, r0, c2bf);
    float b2y = ldf(gbih2, r1, a2bf) + ldf(gbhh2, r1, c2bf);
    float blx = ldf(gblin, lane, blbf);
    float bly = (lane < 16) ? ldf(gblin, lane + 64, blbf) : 0.0f;

#pragma unroll
    for (int k = 0; k < HID; ++k) { pinf(wlx[k]); pinf(wly[k]); }
#pragma unroll
    for (int k = 0; k < DIN; ++k) { pinf(w1x[k]); pinf(w1y[k]); }
    pinf(b1x); pinf(b1y); pinf(b2x); pinf(b2y); pinf(blx); pinf(bly);

    // Per-lane activation constants for the second gate component:
    // low lanes (g gate) need tanh, high lanes (o gate) need sigmoid.
    const float eY = (lane < HID) ? -2.885390082f : -1.442695041f;
    const float mY = (lane < HID) ?  2.0f : 1.0f;
    const float aY = (lane < HID) ? -1.0f : 0.0f;

    // x: 8 values per step, wave-uniform address; width depends on dtype
    const char* xbase = (const char*)gx +
        (size_t)b * TLEN * DIN * (xbf ? 2 : 4);
    auto load_x = [&](float* d, int t) {
        if (xbf) {
            uint4 u = ((const uint4*)xbase)[t];          // 8 bf16 = 16B
            d[0] = bfbits(u.x & 0xffffu); d[1] = bfbits(u.x >> 16);
            d[2] = bfbits(u.y & 0xffffu); d[3] = bfbits(u.y >> 16);
            d[4] = bfbits(u.z & 0xffffu); d[5] = bfbits(u.z >> 16);
            d[6] = bfbits(u.w & 0xffffu); d[7] = bfbits(u.w >> 16);
        } else {
            float4 a = ((const float4*)xbase)[2*t];      // 8 fp32 = 32B
            float4 c = ((const float4*)xbase)[2*t + 1];
            d[0] = a.x; d[1] = a.y; d[2] = a.z; d[3] = a.w;
            d[4] = c.x; d[5] = c.y; d[6] = c.z; d[7] = c.w;
        }
    };
    // bias1 + Wih1 . x — independent of the recurrence
    auto xgate = [&](const float* xv, float& gx_, float& gy_) {
        float axx = 0, ayy = 0, bxx = 0, byy = 0;
#pragma unroll
        for (int k = 0; k < DIN; k += 2) {
            axx = fmaf(w1x[k],   xv[k],   axx);
            ayy = fmaf(w1y[k],   xv[k],   ayy);
            bxx = fmaf(w1x[k+1], xv[k+1], bxx);
            byy = fmaf(w1y[k+1], xv[k+1], byy);
        }
        gx_ = b1x + (axx + bxx);
        gy_ = b1y + (ayy + byy);
    };

    float* outp = gout + (size_t)b * TLEN * DOUT;

    float c1 = 0.0f, c2 = 0.0f;              // valid on lanes<32; junk elsewhere (never read)
    float p1x0 = 0, p1x1 = 0, p1y0 = 0, p1y1 = 0;  // Whh1 . h1_{t-1} partials
    float p2x0 = 0, p2x1 = 0, p2y0 = 0, p2y1 = 0;  // Whh2 . h2_{t-1} partials

    float xn1[DIN], xn2[DIN];
    float g1bx, g1by;
    {
        float x0[DIN];
        load_x(x0, 0);
        load_x(xn1, 1);
        load_x(xn2, 2);
        xgate(x0, g1bx, g1by);
    }

#pragma unroll 1
    for (int t = 0; t < TLEN; ++t) {
        // issue far prefetch early; consumed 2 iterations from now
        float xn3[DIN] = {0,0,0,0,0,0,0,0};
        if (t + 3 < TLEN) load_x(xn3, t + 3);

        // ---- layer-1 gates: pre1 (last iter's round 1) + bias + Wih1.x ----
        float g1x = (p1x0 + p1x1) + g1bx;
        float g1y = (p1y0 + p1y1) + g1by;

        float A1 = fsig(g1x);
        float e1 = __builtin_amdgcn_exp2f(eY * g1y);
        float B1 = fmaf(__builtin_amdgcn_rcpf(1.0f + e1), mY, aY);
        float sf1 = pull_upper(A1, psel);    // sig(f) -> low lanes
        float so1 = pull_upper(B1, psel);    // sig(o) -> low lanes
        c1 = fmaf(sf1, c1, A1 * B1);         // sig(f)*c + sig(i)*tanh(g)
        float ec1 = __builtin_amdgcn_exp2f(-2.885390082f * c1);
        float h1n = so1 * fmaf(__builtin_amdgcn_rcpf(1.0f + ec1), 2.0f, -1.0f);

        // independent filler work: next step's x-gates (uses x(t+1))
        float g1bxn, g1byn;
        xgate(xn1, g1bxn, g1byn);

        // ---- h1 broadcast + round 1: g2 (Wih2, AGPR) AND next pre1 (Whh1, AGPR) ----
        float q0x=0,q1x=0,q2x=0,q3x=0, q0y=0,q1y=0,q2y=0,q3y=0;
        float n0x=0,n1x=0,n2x=0,n3x=0, n0y=0,n1y=0,n2y=0,n3y=0;
#pragma unroll
        for (int k = 0; k < HID; k += 4) {
            float h0 = rdlane(h1n, k);
            float h1v = rdlane(h1n, k + 1);
            float h2v = rdlane(h1n, k + 2);
            float h3v = rdlane(h1n, k + 3);
            float wx, wy;
            AREAD(wx, Aih2x[k  ]); AREAD(wy, Aih2y[k  ]);
            q0x = fmaf(wx, h0, q0x);  q0y = fmaf(wy, h0, q0y);
            AREAD(wx, Ahh1x[k  ]); AREAD(wy, Ahh1y[k  ]);
            n0x = fmaf(wx, h0, n0x);  n0y = fmaf(wy, h0, n0y);
            AREAD(wx, Aih2x[k+1]); AREAD(wy, Aih2y[k+1]);
            q1x = fmaf(wx, h1v, q1x); q1y = fmaf(wy, h1v, q1y);
            AREAD(wx, Ahh1x[k+1]); AREAD(wy, Ahh1y[k+1]);
            n1x = fmaf(wx, h1v, n1x); n1y = fmaf(wy, h1v, n1y);
            AREAD(wx, Aih2x[k+2]); AREAD(wy, Aih2y[k+2]);
            q2x = fmaf(wx, h2v, q2x); q2y = fmaf(wy, h2v, q2y);
            AREAD(wx, Ahh1x[k+2]); AREAD(wy, Ahh1y[k+2]);
            n2x = fmaf(wx, h2v, n2x); n2y = fmaf(wy, h2v, n2y);
            AREAD(wx, Aih2x[k+3]); AREAD(wy, Aih2y[k+3]);
            q3x = fmaf(wx, h3v, q3x); q3y = fmaf(wy, h3v, q3y);
            AREAD(wx, Ahh1x[k+3]); AREAD(wy, Ahh1y[k+3]);
            n3x = fmaf(wx, h3v, n3x); n3y = fmaf(wy, h3v, n3y);
        }
        p1x0 = n0x + n1x; p1x1 = n2x + n3x;
        p1y0 = n0y + n1y; p1y1 = n2y + n3y;
        float g2x = ((q0x + q1x) + (q2x + q3x)) + ((p2x0 + p2x1) + b2x);
        float g2y = ((q0y + q1y) + (q2y + q3y)) + ((p2y0 + p2y1) + b2y);

        // ---- layer-2 cell update ----
        float A2 = fsig(g2x);
        float e2 = __builtin_amdgcn_exp2f(eY * g2y);
        float B2 = fmaf(__builtin_amdgcn_rcpf(1.0f + e2), mY, aY);
        float sf2 = pull_upper(A2, psel);
        float so2 = pull_upper(B2, psel);
        c2 = fmaf(sf2, c2, A2 * B2);
        float ec2 = __builtin_amdgcn_exp2f(-2.885390082f * c2);
        float h2n = so2 * fmaf(__builtin_amdgcn_rcpf(1.0f + ec2), 2.0f, -1.0f);

        // ---- h2 broadcast + round 2: out proj (Wlin, VGPR) AND next pre2 (Whh2, AGPR) ----
        float o0x=blx,o1x=0,o2x=0,o3x=0, o0y=bly,o1y=0,o2y=0,o3y=0;
        float m0x=0,m1x=0,m2x=0,m3x=0, m0y=0,m1y=0,m2y=0,m3y=0;
#pragma unroll
        for (int k = 0; k < HID; k += 4) {
            float h0 = rdlane(h2n, k);
            float h1v = rdlane(h2n, k + 1);
            float h2v = rdlane(h2n, k + 2);
            float h3v = rdlane(h2n, k + 3);
            float wx, wy;
            o0x = fmaf(wlx[k  ], h0, o0x);  o0y = fmaf(wly[k  ], h0, o0y);
            AREAD(wx, Ahh2x[k  ]); AREAD(wy, Ahh2y[k  ]);
            m0x = fmaf(wx, h0, m0x);  m0y = fmaf(wy, h0, m0y);
            o1x = fmaf(wlx[k+1], h1v, o1x); o1y = fmaf(wly[k+1], h1v, o1y);
            AREAD(wx, Ahh2x[k+1]); AREAD(wy, Ahh2y[k+1]);
            m1x = fmaf(wx, h1v, m1x); m1y = fmaf(wy, h1v, m1y);
            o2x = fmaf(wlx[k+2], h2v, o2x); o2y = fmaf(wly[k+2], h2v, o2y);
            AREAD(wx, Ahh2x[k+2]); AREAD(wy, Ahh2y[k+2]);
            m2x = fmaf(wx, h2v, m2x); m2y = fmaf(wy, h2v, m2y);
            o3x = fmaf(wlx[k+3], h3v, o3x); o3y = fmaf(wly[k+3], h3v, o3y);
            AREAD(wx, Ahh2x[k+3]); AREAD(wy, Ahh2y[k+3]);
            m3x = fmaf(wx, h3v, m3x); m3y = fmaf(wy, h3v, m3y);
        }
        p2x0 = m0x + m1x; p2x1 = m2x + m3x;
        p2y0 = m0y + m1y; p2y1 = m2y + m3y;
        float oaccx = (o0x + o1x) + (o2x + o3x);
        float oaccy = (o0y + o1y) + (o2y + o3y);

        float* op = outp + (size_t)t * DOUT;
        op[lane] = oaccx;                       // rows 0..63
        if (lane < 16) op[64 + lane] = oaccy;   // rows 64..79

        // rotate x pipeline
        g1bx = g1bxn; g1by = g1byn;
#pragma unroll
        for (int k = 0; k < DIN; ++k) { xn1[k] = xn2[k]; xn2[k] = xn3[k]; }
    }
}

extern "C" void kernel_launch(void* const* d_in, const int* in_sizes, int n_in,
                              void* d_out, int out_size, void* d_ws, size_t ws_size,
                              hipStream_t stream)
{
    float* out = (float*)d_out;
    const int xelems = in_sizes[0];
    const int B = xelems / (TLEN * DIN);   // 256 (element count, dtype-independent)
    lstm_seq_kernel<<<B, 64, 0, stream>>>(d_in[0], d_in[1], d_in[2], d_in[3],
                                          d_in[4], d_in[5], d_in[6], d_in[7],
                                          d_in[8], d_in[9], d_in[10],
                                          out, xelems);
}